// Round 15
// baseline (100.922 us; speedup 1.0000x reference)
//
#include <hip/hip_runtime.h>
#include <hip/hip_bf16.h>

#define DD 256
#define NROWS 16384
#define TILES 4
#define TROWS 16
#define REPS 8  // diagnostic: in-kernel replay to surface K2 in rocprof top-5

typedef float f32x4 __attribute__((ext_vector_type(4)));
typedef __bf16 bf16x4 __attribute__((ext_vector_type(4)));
typedef __bf16 bf16x8 __attribute__((ext_vector_type(8)));

__device__ __forceinline__ bf16x8 cvt8(f32x4 lo, f32x4 hi) {
  bf16x8 v;
#pragma unroll
  for (int j = 0; j < 4; ++j) {
    v[j] = (__bf16)lo[j];
    v[4 + j] = (__bf16)hi[j];
  }
  return v;
}

// ---------------------------------------------------------------------------
// K1: Wc = Wout @ Wv (bf16), bc = bout + Wout @ bv.  [R13 version, UNCHANGED]
// ---------------------------------------------------------------------------
__global__ __launch_bounds__(1024) void wc_bc_kernel(
    const float* __restrict__ Wqkv, const float* __restrict__ bqkv,
    const float* __restrict__ Wout, const float* __restrict__ bout,
    __bf16* __restrict__ Wc, float* __restrict__ bc) {
  __shared__ f32x4 part[16][64];
  __shared__ float red[4];
  const int i = blockIdx.x;
  const int t = threadIdx.x;
  const int w = t >> 6, l = t & 63;
  const float* __restrict__ Wv = Wqkv + 2 * DD * DD;
  const float* __restrict__ bv = bqkv + 2 * DD;
  const float* __restrict__ wrow = Wout + (size_t)i * DD;

  f32x4 wr[4];
#pragma unroll
  for (int k = 0; k < 4; ++k) wr[k] = *(const f32x4*)(wrow + w * 16 + k * 4);

  const float* wvp = Wv + (size_t)(w * 16) * DD + l * 4;
  f32x4 a0 = {0.f, 0.f, 0.f, 0.f}, a1 = {0.f, 0.f, 0.f, 0.f};
  f32x4 a2 = {0.f, 0.f, 0.f, 0.f}, a3 = {0.f, 0.f, 0.f, 0.f};
#pragma unroll
  for (int k = 0; k < 4; ++k) {
    a0 += wr[k][0] * *(const f32x4*)(wvp + (size_t)(4 * k + 0) * DD);
    a1 += wr[k][1] * *(const f32x4*)(wvp + (size_t)(4 * k + 1) * DD);
    a2 += wr[k][2] * *(const f32x4*)(wvp + (size_t)(4 * k + 2) * DD);
    a3 += wr[k][3] * *(const f32x4*)(wvp + (size_t)(4 * k + 3) * DD);
  }
  part[w][l] = (a0 + a1) + (a2 + a3);

  if (t < 256) {
    float p = wrow[t] * bv[t];
#pragma unroll
    for (int off = 32; off > 0; off >>= 1) p += __shfl_down(p, off);
    if (l == 0) red[w] = p;
  }
  __syncthreads();
  if (w == 0) {
    f32x4 s = {0.f, 0.f, 0.f, 0.f};
#pragma unroll
    for (int k = 0; k < 16; ++k) s += part[k][l];
    bf16x4 o;
#pragma unroll
    for (int j = 0; j < 4; ++j) o[j] = (__bf16)s[j];
    *(bf16x4*)(Wc + (size_t)i * DD + l * 4) = o;
    if (l == 0) bc[i] = bout[i] + red[0] + red[1] + red[2] + red[3];
  }
}

// ---------------------------------------------------------------------------
// K2: out = x + x @ Wc^T + bc.  [R13 body, wrapped in REPS in-kernel replays
// (idempotent; memory-clobber defeats CSE/hoist so each rep is a faithful
// re-execution) -> dispatch ~8x K2 so it ranks top-1 in rocprof and we get
// its MfmaUtil/VALUBusy/FETCH/conflict/occupancy for the first time.]
// ---------------------------------------------------------------------------
__global__ __launch_bounds__(256, 4) void knn_attn_main(
    const float* __restrict__ x, const __bf16* __restrict__ Wc,
    const float* __restrict__ bc, float* __restrict__ out) {
  __shared__ __bf16 xs[2][TROWS * DD];  // 2 x 8 KiB, swizzled

  const int t = threadIdx.x;
  const int w = t >> 6, l = t & 63;
  const int cg = blockIdx.x >> 8;
  const int rb = blockIdx.x & 255;
  const int C0 = cg * 64;
  const int Rbase = rb * (TILES * TROWS);

  const int xrow = l & 15, g4 = l >> 4;
  const int rsw = (xrow & 7) << 4;
  const int rA = w * 16 + xrow;
  const int ocol = C0 + w * 16 + g4 * 4;

  const int sr = t >> 4, sc = t & 15;
  const int ssw = (sr & 7) << 4;
  const int sbase = sr * 512 + sc * 32;

  for (int rep = 0; rep < REPS; ++rep) {
    asm volatile("" ::: "memory");  // force faithful re-execution (rule 17)

    bf16x8 af[8];
    {
      const __bf16* wrp = Wc + (size_t)(C0 + rA) * DD + g4 * 8;
#pragma unroll
      for (int ks = 0; ks < 8; ++ks) af[ks] = *(const bf16x8*)(wrp + ks * 32);
    }
    const f32x4 bias = *(const f32x4*)(bc + ocol);

    {
      const float* s0 = x + (size_t)(Rbase + sr) * DD + sc * 16;
      f32x4 a = *(const f32x4*)(s0 + 0);
      f32x4 b = *(const f32x4*)(s0 + 4);
      f32x4 c = *(const f32x4*)(s0 + 8);
      f32x4 d = *(const f32x4*)(s0 + 12);
      char* xb = (char*)&xs[0][0];
      *(bf16x8*)(xb + ((sbase + 0) ^ ssw)) = cvt8(a, b);
      *(bf16x8*)(xb + ((sbase + 16) ^ ssw)) = cvt8(c, d);
    }
    __syncthreads();

    for (int i = 0; i < TILES; ++i) {
      f32x4 a, b, c, d;
      if (i + 1 < TILES) {
        const float* sn =
            x + (size_t)(Rbase + (i + 1) * TROWS + sr) * DD + sc * 16;
        a = *(const f32x4*)(sn + 0);
        b = *(const f32x4*)(sn + 4);
        c = *(const f32x4*)(sn + 8);
        d = *(const f32x4*)(sn + 12);
      }

      const char* xb = (const char*)&xs[i & 1][0];
      f32x4 acc = {0.f, 0.f, 0.f, 0.f};
#pragma unroll
      for (int ks = 0; ks < 8; ++ks) {
        const int kb = ks * 64 + g4 * 16;
        bf16x8 bfr = *(const bf16x8*)(xb + ((xrow * 512 + kb) ^ rsw));
        acc = __builtin_amdgcn_mfma_f32_16x16x32_bf16(af[ks], bfr, acc, 0, 0, 0);
      }
      {
        const size_t idx = (size_t)(Rbase + i * TROWS + xrow) * DD + ocol;
        f32x4 xres = *(const f32x4*)(x + idx);
        *(f32x4*)(out + idx) = acc + xres + bias;
      }

      if (i + 1 < TILES) {
        char* xbn = (char*)&xs[(i + 1) & 1][0];
        *(bf16x8*)(xbn + ((sbase + 0) ^ ssw)) = cvt8(a, b);
        *(bf16x8*)(xbn + ((sbase + 16) ^ ssw)) = cvt8(c, d);
      }
      __syncthreads();
    }
  }
}

extern "C" void kernel_launch(void* const* d_in, const int* in_sizes, int n_in,
                              void* d_out, int out_size, void* d_ws, size_t ws_size,
                              hipStream_t stream) {
  const float* x = (const float*)d_in[0];
  const float* Wqkv = (const float*)d_in[1];
  const float* bqkv = (const float*)d_in[2];
  const float* Wout = (const float*)d_in[3];
  const float* bout = (const float*)d_in[4];
  float* out = (float*)d_out;

  __bf16* Wc = (__bf16*)d_ws;                                   // 128 KiB
  float* bc = (float*)((char*)d_ws + DD * DD * sizeof(__bf16)); // +1 KiB

  wc_bc_kernel<<<DD, 1024, 0, stream>>>(Wqkv, bqkv, Wout, bout, Wc, bc);
  knn_attn_main<<<1024, 256, 0, stream>>>(x, Wc, bc, out);
}

// Round 16
// 24.954 us; speedup vs baseline: 4.0443x; 4.0443x over previous
//
#include <hip/hip_runtime.h>
#include <hip/hip_bf16.h>

#define DD 256
#define NROWS 16384
#define TILES 2
#define TROWS 16

typedef float f32x4 __attribute__((ext_vector_type(4)));
typedef __bf16 bf16x4 __attribute__((ext_vector_type(4)));
typedef __bf16 bf16x8 __attribute__((ext_vector_type(8)));

__device__ __forceinline__ bf16x8 cvt8(f32x4 lo, f32x4 hi) {
  bf16x8 v;
#pragma unroll
  for (int j = 0; j < 4; ++j) {
    v[j] = (__bf16)lo[j];
    v[4 + j] = (__bf16)hi[j];
  }
  return v;
}

// ---------------------------------------------------------------------------
// K1: Wc = Wout @ Wv (bf16), bc = bout + Wout @ bv.
// 64 blocks x 1024 thr, 4 Wc rows/block: Wv read ONCE per block -> 16 MB
// aggregate L3 traffic (R13's 256-block version re-read Wv per block: 64 MB,
// ~3.5us L3-bound -- the measured D1=4.3us). Wave w owns Wv rows [16w,+16);
// lane l owns cols 4l..4l+3; coeffs in regs; 64KB LDS tree reduce.
// ---------------------------------------------------------------------------
__global__ __launch_bounds__(1024) void wc_bc_kernel(
    const float* __restrict__ Wqkv, const float* __restrict__ bqkv,
    const float* __restrict__ Wout, const float* __restrict__ bout,
    __bf16* __restrict__ Wc, float* __restrict__ bc) {
  __shared__ f32x4 part[16][4][64];  // 64 KiB
  __shared__ float red[4];
  const int i0 = blockIdx.x * 4;
  const int t = threadIdx.x;
  const int w = t >> 6, l = t & 63;
  const float* __restrict__ Wv = Wqkv + 2 * DD * DD;
  const float* __restrict__ bv = bqkv + 2 * DD;

  // wave-uniform Wout coefficients for this wave's d-slice [16w, +16)
  f32x4 wrc[4][4];
#pragma unroll
  for (int r = 0; r < 4; ++r)
#pragma unroll
    for (int kk = 0; kk < 4; ++kk)
      wrc[r][kk] = *(const f32x4*)(Wout + (size_t)(i0 + r) * DD + w * 16 + kk * 4);

  const float* wvp = Wv + (size_t)(w * 16) * DD + l * 4;
  f32x4 a0 = {0.f, 0.f, 0.f, 0.f}, a1 = {0.f, 0.f, 0.f, 0.f};
  f32x4 a2 = {0.f, 0.f, 0.f, 0.f}, a3 = {0.f, 0.f, 0.f, 0.f};
#pragma unroll
  for (int k = 0; k < 16; ++k) {
    f32x4 wv = *(const f32x4*)(wvp + (size_t)k * DD);  // 16 indep 1KB/wave loads
    a0 += wv * wrc[0][k >> 2][k & 3];
    a1 += wv * wrc[1][k >> 2][k & 3];
    a2 += wv * wrc[2][k >> 2][k & 3];
    a3 += wv * wrc[3][k >> 2][k & 3];
  }
  part[w][0][l] = a0;
  part[w][1][l] = a1;
  part[w][2][l] = a2;
  part[w][3][l] = a3;

  if (t >= 256 && t < 512) {  // bc partials (waves 4-7)
    const int r = (t >> 6) - 4, ll = t & 63;
    float p = 0.f;
#pragma unroll
    for (int k = 0; k < 4; ++k)
      p += Wout[(size_t)(i0 + r) * DD + k * 64 + ll] * bv[k * 64 + ll];
#pragma unroll
    for (int off = 32; off > 0; off >>= 1) p += __shfl_down(p, off);
    if (ll == 0) red[r] = p;
  }
  __syncthreads();
  if (t < 256) {
    const int r = t >> 6, q = t & 63;
    f32x4 s = {0.f, 0.f, 0.f, 0.f};
#pragma unroll
    for (int k = 0; k < 16; ++k) s += part[k][r][q];
    bf16x4 o;
#pragma unroll
    for (int j = 0; j < 4; ++j) o[j] = (__bf16)s[j];
    *(bf16x4*)(Wc + (size_t)(i0 + r) * DD + q * 4) = o;
  }
  if (t < 4) bc[i0 + t] = bout[i0 + t] + red[t];
}

// ---------------------------------------------------------------------------
// K2: out = x + x @ Wc^T + bc.
// R15 counters: MfmaUtil 7%, VALU 5%, HBM 20%, occ 38% -> latency-bound, TLP
// is the lever. vs R13: TILES=2, grid 2048 (4cg x 512rb), launch_bounds
// (256,6) + 16KB LDS -> 6 blocks/CU = 24 waves/CU (was ~12); residual read
// from LDS bf16 tile (not global, shortens inter-barrier path); staging
// ds_writes redistributed to 16B stride (conflict-free, was 4-way-ish).
// Blocks sharing x rows: bid = rb + 512k == rb mod 8 -> same XCD L2.
// ---------------------------------------------------------------------------
__global__ __launch_bounds__(256, 6) void knn_attn_main(
    const float* __restrict__ x, const __bf16* __restrict__ Wc,
    const float* __restrict__ bc, float* __restrict__ out) {
  __shared__ __bf16 xs[2][TROWS * DD];  // 2 x 8 KiB, swizzled

  const int t = threadIdx.x;
  const int w = t >> 6, l = t & 63;
  const int cg = blockIdx.x >> 9;   // 0..3
  const int rb = blockIdx.x & 511;  // 0..511
  const int C0 = cg * 64;
  const int Rbase = rb * (TILES * TROWS);  // 32 rows/block

  const int xrow = l & 15, g4 = l >> 4;
  const int rsw = (xrow & 7) << 4;
  const int rA = w * 16 + xrow;
  const int ocol = C0 + w * 16 + g4 * 4;

  bf16x8 af[8];  // weight fragments, fixed per lane for the whole block
  {
    const __bf16* wrp = Wc + (size_t)(C0 + rA) * DD + g4 * 8;
#pragma unroll
    for (int ks = 0; ks < 8; ++ks) af[ks] = *(const bf16x8*)(wrp + ks * 32);
  }
  const f32x4 bias = *(const f32x4*)(bc + ocol);  // includes bout

  // staging: thread t -> row sr, two 16B LDS chunks at sc*16 and sc*16+256
  // (16B stride across lanes: every bank exactly 8 accesses -> conflict-free)
  const int sr = t >> 4, sc = t & 15;
  const int ssw = (sr & 7) << 4;
  const int cb0 = sr * 512 + sc * 16;

  {  // prologue: tile 0 (global loads: 2x32B contiguous per lane)
    const float* src = x + (size_t)(Rbase + sr) * DD + sc * 8;
    f32x4 a = *(const f32x4*)(src);
    f32x4 b = *(const f32x4*)(src + 4);
    f32x4 c = *(const f32x4*)(src + 128);
    f32x4 d = *(const f32x4*)(src + 132);
    char* xb = (char*)&xs[0][0];
    *(bf16x8*)(xb + ((cb0 + 0) ^ ssw)) = cvt8(a, b);
    *(bf16x8*)(xb + ((cb0 + 256) ^ ssw)) = cvt8(c, d);
  }
  __syncthreads();

  for (int i = 0; i < TILES; ++i) {
    f32x4 a, b, c, d;
    if (i + 1 < TILES) {  // next tile's loads fly under compute
      const float* sn = x + (size_t)(Rbase + (i + 1) * TROWS + sr) * DD + sc * 8;
      a = *(const f32x4*)(sn);
      b = *(const f32x4*)(sn + 4);
      c = *(const f32x4*)(sn + 128);
      d = *(const f32x4*)(sn + 132);
    }

    const char* xb = (const char*)&xs[i & 1][0];
    f32x4 acc = {0.f, 0.f, 0.f, 0.f};
#pragma unroll
    for (int ks = 0; ks < 8; ++ks) {
      const int kb = ks * 64 + g4 * 16;
      bf16x8 bfr = *(const bf16x8*)(xb + ((xrow * 512 + kb) ^ rsw));
      acc = __builtin_amdgcn_mfma_f32_16x16x32_bf16(af[ks], bfr, acc, 0, 0, 0);
    }
    {  // epilogue: residual from LDS (bf16 x; +<=0.009 absmax, margin 5x)
      bf16x4 xr4 = *(const bf16x4*)(xb + ((xrow * 512 + ocol * 2) ^ rsw));
      f32x4 xres;
#pragma unroll
      for (int j = 0; j < 4; ++j) xres[j] = (float)xr4[j];
      *(f32x4*)(out + (size_t)(Rbase + i * TROWS + xrow) * DD + ocol) =
          acc + xres + bias;
    }

    if (i + 1 < TILES) {
      char* xbn = (char*)&xs[(i + 1) & 1][0];
      *(bf16x8*)(xbn + ((cb0 + 0) ^ ssw)) = cvt8(a, b);
      *(bf16x8*)(xbn + ((cb0 + 256) ^ ssw)) = cvt8(c, d);
    }
    __syncthreads();
  }
}

extern "C" void kernel_launch(void* const* d_in, const int* in_sizes, int n_in,
                              void* d_out, int out_size, void* d_ws, size_t ws_size,
                              hipStream_t stream) {
  const float* x = (const float*)d_in[0];
  const float* Wqkv = (const float*)d_in[1];
  const float* bqkv = (const float*)d_in[2];
  const float* Wout = (const float*)d_in[3];
  const float* bout = (const float*)d_in[4];
  float* out = (float*)d_out;

  __bf16* Wc = (__bf16*)d_ws;                                   // 128 KiB
  float* bc = (float*)((char*)d_ws + DD * DD * sizeof(__bf16)); // +1 KiB

  wc_bc_kernel<<<64, 1024, 0, stream>>>(Wqkv, bqkv, Wout, bout, Wc, bc);
  knn_attn_main<<<2048, 256, 0, stream>>>(x, Wc, bc, out);
}

// Round 17
// 22.347 us; speedup vs baseline: 4.5162x; 1.1167x over previous
//
#include <hip/hip_runtime.h>
#include <hip/hip_bf16.h>

#define DD 256
#define NROWS 16384
#define TILES 2
#define TROWS 16

typedef float f32x4 __attribute__((ext_vector_type(4)));
typedef __bf16 bf16x4 __attribute__((ext_vector_type(4)));
typedef __bf16 bf16x8 __attribute__((ext_vector_type(8)));

__device__ __forceinline__ bf16x8 cvt8(f32x4 lo, f32x4 hi) {
  bf16x8 v;
#pragma unroll
  for (int j = 0; j < 4; ++j) {
    v[j] = (__bf16)lo[j];
    v[4 + j] = (__bf16)hi[j];
  }
  return v;
}

// ---------------------------------------------------------------------------
// K1: Wc = Wout @ Wv (bf16), bc = bout + Wout @ bv.  [R13 version VERBATIM --
// measured D1 = 4.3us; R16's 64-block rebuild regressed, reverted.]
// ---------------------------------------------------------------------------
__global__ __launch_bounds__(1024) void wc_bc_kernel(
    const float* __restrict__ Wqkv, const float* __restrict__ bqkv,
    const float* __restrict__ Wout, const float* __restrict__ bout,
    __bf16* __restrict__ Wc, float* __restrict__ bc) {
  __shared__ f32x4 part[16][64];
  __shared__ float red[4];
  const int i = blockIdx.x;
  const int t = threadIdx.x;
  const int w = t >> 6, l = t & 63;
  const float* __restrict__ Wv = Wqkv + 2 * DD * DD;
  const float* __restrict__ bv = bqkv + 2 * DD;
  const float* __restrict__ wrow = Wout + (size_t)i * DD;

  f32x4 wr[4];
#pragma unroll
  for (int k = 0; k < 4; ++k) wr[k] = *(const f32x4*)(wrow + w * 16 + k * 4);

  const float* wvp = Wv + (size_t)(w * 16) * DD + l * 4;
  f32x4 a0 = {0.f, 0.f, 0.f, 0.f}, a1 = {0.f, 0.f, 0.f, 0.f};
  f32x4 a2 = {0.f, 0.f, 0.f, 0.f}, a3 = {0.f, 0.f, 0.f, 0.f};
#pragma unroll
  for (int k = 0; k < 4; ++k) {
    a0 += wr[k][0] * *(const f32x4*)(wvp + (size_t)(4 * k + 0) * DD);
    a1 += wr[k][1] * *(const f32x4*)(wvp + (size_t)(4 * k + 1) * DD);
    a2 += wr[k][2] * *(const f32x4*)(wvp + (size_t)(4 * k + 2) * DD);
    a3 += wr[k][3] * *(const f32x4*)(wvp + (size_t)(4 * k + 3) * DD);
  }
  part[w][l] = (a0 + a1) + (a2 + a3);

  if (t < 256) {
    float p = wrow[t] * bv[t];
#pragma unroll
    for (int off = 32; off > 0; off >>= 1) p += __shfl_down(p, off);
    if (l == 0) red[w] = p;
  }
  __syncthreads();
  if (w == 0) {
    f32x4 s = {0.f, 0.f, 0.f, 0.f};
#pragma unroll
    for (int k = 0; k < 16; ++k) s += part[k][l];
    bf16x4 o;
#pragma unroll
    for (int j = 0; j < 4; ++j) o[j] = (__bf16)s[j];
    *(bf16x4*)(Wc + (size_t)i * DD + l * 4) = o;
    if (l == 0) bc[i] = bout[i] + red[0] + red[1] + red[2] + red[3];
  }
}

// ---------------------------------------------------------------------------
// K2: out = x + x @ Wc^T + bc.  FULL-WIDTH blocks (structural change):
// block = 32 rows x ALL 256 cols; wave w owns cols [64w,+64) with weight
// frags for all 4 col-tiles HOISTED to regs (af[4][8], 128 VGPR).
// Per tile phase/wave: 8 ds_read_b128 -> 32 MFMA (4x density vs R13),
// x staged ONCE (R13 staged it 4x across colgroups), residual from LDS
// bf16 tile (removes exposed L3 read per tile; absmax +<=0.009, margin 5x).
// Grid 512 = 2 blocks/CU exactly resident; launch_bounds(256,2) caps VGPR
// at 256 (est ~230, no spill).
// ---------------------------------------------------------------------------
__global__ __launch_bounds__(256, 2) void knn_attn_main(
    const float* __restrict__ x, const __bf16* __restrict__ Wc,
    const float* __restrict__ bc, float* __restrict__ out) {
  __shared__ __bf16 xs[2][TROWS * DD];  // 2 x 8 KiB, swizzled

  const int t = threadIdx.x;
  const int w = t >> 6, l = t & 63;
  const int Rbase = blockIdx.x * (TILES * TROWS);  // 32 rows/block

  const int xrow = l & 15, g4 = l >> 4;
  const int rsw = (xrow & 7) << 4;

  // Weight fragments for all 4 column tiles of this wave (held whole kernel).
  bf16x8 af[4][8];
  f32x4 bias[4];
#pragma unroll
  for (int ct = 0; ct < 4; ++ct) {
    const __bf16* wrp = Wc + (size_t)(w * 64 + ct * 16 + xrow) * DD + g4 * 8;
#pragma unroll
    for (int ks = 0; ks < 8; ++ks) af[ct][ks] = *(const bf16x8*)(wrp + ks * 32);
    bias[ct] = *(const f32x4*)(bc + w * 64 + ct * 16 + g4 * 4);  // incl. bout
  }

  // staging geometry (R13-verified): thread -> (row sr, 16-float seg sc)
  const int sr = t >> 4, sc = t & 15;
  const int ssw = (sr & 7) << 4;
  const int sbase = sr * 512 + sc * 32;

  {  // prologue: tile 0
    const float* s0 = x + (size_t)(Rbase + sr) * DD + sc * 16;
    f32x4 a = *(const f32x4*)(s0 + 0);
    f32x4 b = *(const f32x4*)(s0 + 4);
    f32x4 c = *(const f32x4*)(s0 + 8);
    f32x4 d = *(const f32x4*)(s0 + 12);
    char* xb = (char*)&xs[0][0];
    *(bf16x8*)(xb + ((sbase + 0) ^ ssw)) = cvt8(a, b);
    *(bf16x8*)(xb + ((sbase + 16) ^ ssw)) = cvt8(c, d);
  }
  __syncthreads();

  for (int i = 0; i < TILES; ++i) {
    f32x4 a, b, c, d;
    if (i + 1 < TILES) {  // next tile's loads fly under the 32-MFMA phase
      const float* sn =
          x + (size_t)(Rbase + (i + 1) * TROWS + sr) * DD + sc * 16;
      a = *(const f32x4*)(sn + 0);
      b = *(const f32x4*)(sn + 4);
      c = *(const f32x4*)(sn + 8);
      d = *(const f32x4*)(sn + 12);
    }

    const char* xb = (const char*)&xs[i & 1][0];
    // x fragments read ONCE, reused by all 4 column tiles (32 MFMA).
    bf16x8 xf[8];
#pragma unroll
    for (int ks = 0; ks < 8; ++ks)
      xf[ks] = *(const bf16x8*)(xb + ((xrow * 512 + ks * 64 + g4 * 16) ^ rsw));

#pragma unroll
    for (int ct = 0; ct < 4; ++ct) {
      f32x4 acc = {0.f, 0.f, 0.f, 0.f};
#pragma unroll
      for (int ks = 0; ks < 8; ++ks)
        acc = __builtin_amdgcn_mfma_f32_16x16x32_bf16(af[ct][ks], xf[ks], acc, 0, 0, 0);
      // epilogue: D col(l&15)=x-row, rowquad g4*4+reg = out-col (verified);
      // residual from LDS bf16 tile.
      const int ocol = w * 64 + ct * 16 + g4 * 4;
      bf16x4 xr4 = *(const bf16x4*)(xb + ((xrow * 512 + ocol * 2) ^ rsw));
      f32x4 xres;
#pragma unroll
      for (int j = 0; j < 4; ++j) xres[j] = (float)xr4[j];
      *(f32x4*)(out + (size_t)(Rbase + i * TROWS + xrow) * DD + ocol) =
          acc + xres + bias[ct];
    }

    if (i + 1 < TILES) {  // publish next tile (vmcnt wait lands post-MFMA)
      char* xbn = (char*)&xs[(i + 1) & 1][0];
      *(bf16x8*)(xbn + ((sbase + 0) ^ ssw)) = cvt8(a, b);
      *(bf16x8*)(xbn + ((sbase + 16) ^ ssw)) = cvt8(c, d);
    }
    __syncthreads();
  }
}

extern "C" void kernel_launch(void* const* d_in, const int* in_sizes, int n_in,
                              void* d_out, int out_size, void* d_ws, size_t ws_size,
                              hipStream_t stream) {
  const float* x = (const float*)d_in[0];
  const float* Wqkv = (const float*)d_in[1];
  const float* bqkv = (const float*)d_in[2];
  const float* Wout = (const float*)d_in[3];
  const float* bout = (const float*)d_in[4];
  float* out = (float*)d_out;

  __bf16* Wc = (__bf16*)d_ws;                                   // 128 KiB
  float* bc = (float*)((char*)d_ws + DD * DD * sizeof(__bf16)); // +1 KiB

  wc_bc_kernel<<<DD, 1024, 0, stream>>>(Wqkv, bqkv, Wout, bout, Wc, bc);
  knn_attn_main<<<NROWS / (TILES * TROWS), 256, 0, stream>>>(x, Wc, bc, out);
}